// Round 1
// baseline (344.885 us; speedup 1.0000x reference)
//
#include <hip/hip_runtime.h>
#include <hip/hip_bf16.h>
#include <math.h>

// Problem constants (fixed by reference).
constexpr int NVOX = 40000;
constexpr int NQRY = 8192;
constexpr int KK   = 96;
constexpr int CH   = 128;
constexpr int FFD  = 256;

// ---------------------------------------------------------------------------
// Kernel 1: per-voxel — LayerNorm(voxel_features) + relu(coords@k_pos_w.T+b),
// then project the sum through wk and wv (in_w rows 128..383).
// 8 voxels per block of 256 threads.
// ---------------------------------------------------------------------------
__global__ __launch_bounds__(256) void k_voxel(
    const float* __restrict__ vfeat, const float* __restrict__ vcoord,
    const float* __restrict__ n1g, const float* __restrict__ n1b,
    const float* __restrict__ kpw, const float* __restrict__ kpb,
    const float* __restrict__ in_w, const float* __restrict__ in_b,
    float* __restrict__ Kp, float* __restrict__ Vp) {
  __shared__ float g[8][CH];
  const int t = threadIdx.x;
  const int vbase = blockIdx.x * 8;
  {
    const int grp  = t >> 5;   // voxel within block
    const int lane = t & 31;   // handles channels lane*4 .. lane*4+3
    const int j = vbase + grp;
    const float4 x = reinterpret_cast<const float4*>(vfeat + (size_t)j * CH)[lane];
    float s  = x.x + x.y + x.z + x.w;
    float ss = x.x*x.x + x.y*x.y + x.z*x.z + x.w*x.w;
    #pragma unroll
    for (int m = 16; m >= 1; m >>= 1) { s += __shfl_xor(s, m); ss += __shfl_xor(ss, m); }
    const float mean = s * (1.0f/CH);
    const float var  = ss * (1.0f/CH) - mean*mean;
    const float rstd = 1.0f / sqrtf(var + 1e-5f);
    const float c0 = vcoord[j*3+0], c1 = vcoord[j*3+1], c2 = vcoord[j*3+2];
    const int cb = lane*4;
    const float xv[4] = {x.x, x.y, x.z, x.w};
    float4 gv;
    float* gp = &gv.x;
    #pragma unroll
    for (int u = 0; u < 4; u++) {
      const int c = cb + u;
      const float vf = (xv[u] - mean) * rstd * n1g[c] + n1b[c];
      float kp = fmaf(c0, kpw[c*3+0], fmaf(c1, kpw[c*3+1], fmaf(c2, kpw[c*3+2], kpb[c])));
      gp[u] = vf + fmaxf(kp, 0.0f);
    }
    *reinterpret_cast<float4*>(&g[grp][cb]) = gv;   // b128, conflict-free
  }
  __syncthreads();
  // Projection: thread t -> output channel oc of K (t<128) or V (t>=128).
  const int oc  = t & 127;
  const int isv = t >> 7;
  const float* wrow = in_w + (size_t)(CH + isv*CH + oc) * CH;
  const float bia = in_b[CH + isv*CH + oc];
  float acc[8];
  #pragma unroll
  for (int v = 0; v < 8; v++) acc[v] = bia;
  for (int c = 0; c < CH; c += 4) {
    const float4 w4 = *reinterpret_cast<const float4*>(wrow + c);
    #pragma unroll
    for (int v = 0; v < 8; v++) {
      const float4 g4 = *reinterpret_cast<const float4*>(&g[v][c]);  // broadcast
      acc[v] = fmaf(g4.x, w4.x, fmaf(g4.y, w4.y, fmaf(g4.z, w4.z, fmaf(g4.w, w4.w, acc[v]))));
    }
  }
  float* dst = isv ? Vp : Kp;
  #pragma unroll
  for (int v = 0; v < 8; v++) dst[(size_t)(vbase+v)*CH + oc] = acc[v];
}

// ---------------------------------------------------------------------------
// Kernel 2: per-query — q = relu(qc@q_pos_w.T + b) @ wq.T + bq.
// 16 queries per block of 256 threads.
// ---------------------------------------------------------------------------
__global__ __launch_bounds__(256) void k_query(
    const float* __restrict__ qcoord,
    const float* __restrict__ qpw, const float* __restrict__ qpb,
    const float* __restrict__ in_w, const float* __restrict__ in_b,
    float* __restrict__ qout) {
  __shared__ float qf[16][CH];
  const int t = threadIdx.x;
  const int qbase = blockIdx.x * 16;
  #pragma unroll
  for (int i = 0; i < 8; i++) {
    const int e = t + 256*i;
    const int qv = e >> 7, c = e & 127;
    const int qq = qbase + qv;
    const float v = fmaf(qcoord[qq*3+0], qpw[c*3+0],
                    fmaf(qcoord[qq*3+1], qpw[c*3+1],
                    fmaf(qcoord[qq*3+2], qpw[c*3+2], qpb[c])));
    qf[qv][c] = fmaxf(v, 0.0f);
  }
  __syncthreads();
  const int oc = t & 127, half = t >> 7;
  const float* wrow = in_w + (size_t)oc * CH;   // wq = in_w rows 0..127
  const float bia = in_b[oc];
  float acc[8];
  #pragma unroll
  for (int v = 0; v < 8; v++) acc[v] = bia;
  for (int c = 0; c < CH; c += 4) {
    const float4 w4 = *reinterpret_cast<const float4*>(wrow + c);
    #pragma unroll
    for (int v = 0; v < 8; v++) {
      const float4 g4 = *reinterpret_cast<const float4*>(&qf[half*8+v][c]);
      acc[v] = fmaf(g4.x, w4.x, fmaf(g4.y, w4.y, fmaf(g4.z, w4.z, fmaf(g4.w, w4.w, acc[v]))));
    }
  }
  #pragma unroll
  for (int v = 0; v < 8; v++) qout[(size_t)(qbase + half*8 + v)*CH + oc] = acc[v];
}

// ---------------------------------------------------------------------------
// Kernel 3: attention — one block (256 threads) per query.
// scores (8h x 96k) -> masked softmax -> ctx = attn @ V_gather.
// sc stride 100 breaks the 96-stride bank aliasing (96%32==0).
// ---------------------------------------------------------------------------
__global__ __launch_bounds__(256) void k_attn(
    const float* __restrict__ Kp, const float* __restrict__ Vp,
    const float* __restrict__ qg, const int* __restrict__ kidx,
    float* __restrict__ ctxg) {
  __shared__ float qs[CH];
  __shared__ int   js[KK];
  __shared__ float sc[8*100];
  __shared__ float red[2][CH];
  __shared__ float rden[8];
  const int n = blockIdx.x;
  const int t = threadIdx.x;
  if (t < CH) qs[t] = qg[(size_t)n*CH + t];
  if (t < KK) js[t] = kidx[(size_t)n*KK + t];
  __syncthreads();
  // scores: 768 entries, 8 consecutive threads share one key row (512B coalesced)
  #pragma unroll
  for (int i = 0; i < 3; i++) {
    const int e = t + 256*i;
    const int k = e >> 3, h = e & 7;
    const int j = js[k];
    float s;
    if (j < 0) {
      s = -1e9f;
    } else {
      const float* kr = Kp + (size_t)j*CH + h*16;
      const float* qh = qs + h*16;
      s = 0.0f;
      #pragma unroll
      for (int d = 0; d < 16; d += 4) {
        const float4 kv = *reinterpret_cast<const float4*>(kr + d);
        s = fmaf(qh[d], kv.x, fmaf(qh[d+1], kv.y, fmaf(qh[d+2], kv.z, fmaf(qh[d+3], kv.w, s))));
      }
      s *= 0.25f;   // 1/sqrt(16)
    }
    sc[h*100 + k] = s;
  }
  __syncthreads();
  // softmax per head: 16 lanes per head over 96 keys
  if (t < 128) {
    const int h = t >> 4, l = t & 15;
    float mx = -3e38f;
    for (int k = l; k < KK; k += 16) mx = fmaxf(mx, sc[h*100+k]);
    #pragma unroll
    for (int m = 8; m >= 1; m >>= 1) mx = fmaxf(mx, __shfl_xor(mx, m));
    float sum = 0.0f;
    for (int k = l; k < KK; k += 16) {
      const float p = __expf(sc[h*100+k] - mx);   // masked -> exactly 0 (underflow)
      sc[h*100+k] = p;
      sum += p;
    }
    #pragma unroll
    for (int m = 8; m >= 1; m >>= 1) sum += __shfl_xor(sum, m);
    if (l == 0) rden[h] = 1.0f / sum;
  }
  __syncthreads();
  // ctx: thread -> channel c; two key-halves across thread halves
  {
    const int c = t & 127, half = t >> 7;
    const int h = c >> 4;
    float acc = 0.0f;
    for (int k = half*48; k < half*48 + 48; k++) {
      const int j = js[k];            // wave-uniform branch
      if (j >= 0) acc = fmaf(sc[h*100+k], Vp[(size_t)j*CH + c], acc);
    }
    red[half][c] = acc;
  }
  __syncthreads();
  if (t < 128) {
    ctxg[(size_t)n*CH + t] = (red[0][t] + red[1][t]) * rden[t>>4];
  }
}

// ---------------------------------------------------------------------------
// Kernel 4: epilogue — attend = ctx@out_w.T+b; LN2; FFN; residual; final+relu.
// 16 queries per block of 256 threads; everything staged in LDS.
// ---------------------------------------------------------------------------
__global__ __launch_bounds__(256) void k_epi(
    const float* __restrict__ ctxg,
    const float* __restrict__ ow, const float* __restrict__ ob,
    const float* __restrict__ n2g, const float* __restrict__ n2b,
    const float* __restrict__ l1w, const float* __restrict__ l1b,
    const float* __restrict__ l2w, const float* __restrict__ l2b,
    const float* __restrict__ fw, const float* __restrict__ fb,
    float* __restrict__ outp) {
  __shared__ float cs[16][CH];
  __shared__ float as[16][132];   // attend (pad 132: LN stride-16 reads conflict-free)
  __shared__ float hs[16][132];   // LN output, later reused for x = attend+act
  __shared__ float a1[16][FFD];
  const int t = threadIdx.x;
  const int qbase = blockIdx.x * 16;
  #pragma unroll
  for (int i = 0; i < 8; i++) {
    const int e = t + 256*i;
    const int qv = e >> 7, c = e & 127;
    cs[qv][c] = ctxg[(size_t)(qbase+qv)*CH + c];
  }
  __syncthreads();
  const int oc = t & 127, halfq = t >> 7;
  { // attend = cs @ ow.T + ob
    const float* wrow = ow + (size_t)oc * CH;
    const float bia = ob[oc];
    float acc[8];
    #pragma unroll
    for (int v = 0; v < 8; v++) acc[v] = bia;
    for (int c = 0; c < CH; c += 4) {
      const float4 w4 = *reinterpret_cast<const float4*>(wrow + c);
      #pragma unroll
      for (int v = 0; v < 8; v++) {
        const float4 g4 = *reinterpret_cast<const float4*>(&cs[halfq*8+v][c]);
        acc[v] = fmaf(g4.x, w4.x, fmaf(g4.y, w4.y, fmaf(g4.z, w4.z, fmaf(g4.w, w4.w, acc[v]))));
      }
    }
    #pragma unroll
    for (int v = 0; v < 8; v++) as[halfq*8+v][oc] = acc[v];
  }
  __syncthreads();
  { // LayerNorm2: 16 lanes per row
    const int row = t >> 4, l = t & 15;
    float s = 0.0f, ss = 0.0f;
    for (int c = l; c < CH; c += 16) { const float x = as[row][c]; s += x; ss += x*x; }
    #pragma unroll
    for (int m = 8; m >= 1; m >>= 1) { s += __shfl_xor(s, m); ss += __shfl_xor(ss, m); }
    const float mean = s * (1.0f/CH);
    const float var  = ss * (1.0f/CH) - mean*mean;
    const float rstd = 1.0f / sqrtf(var + 1e-5f);
    for (int c = l; c < CH; c += 16)
      hs[row][c] = (as[row][c] - mean) * rstd * n2g[c] + n2b[c];
  }
  __syncthreads();
  { // act1 = relu(hs @ l1w.T + l1b): thread t = ff channel
    const float* wrow = l1w + (size_t)t * CH;
    const float bia = l1b[t];
    float acc[16];
    #pragma unroll
    for (int v = 0; v < 16; v++) acc[v] = bia;
    for (int c = 0; c < CH; c += 4) {
      const float4 w4 = *reinterpret_cast<const float4*>(wrow + c);
      #pragma unroll
      for (int v = 0; v < 16; v++) {
        const float4 g4 = *reinterpret_cast<const float4*>(&hs[v][c]);
        acc[v] = fmaf(g4.x, w4.x, fmaf(g4.y, w4.y, fmaf(g4.z, w4.z, fmaf(g4.w, w4.w, acc[v]))));
      }
    }
    #pragma unroll
    for (int v = 0; v < 16; v++) a1[v][t] = fmaxf(acc[v], 0.0f);
  }
  __syncthreads();
  { // x = attend + a1 @ l2w.T + l2b  -> store into hs (reuse)
    const float* wrow = l2w + (size_t)oc * FFD;
    const float bia = l2b[oc];
    float acc[8];
    #pragma unroll
    for (int v = 0; v < 8; v++) acc[v] = bia;
    for (int c = 0; c < FFD; c += 4) {
      const float4 w4 = *reinterpret_cast<const float4*>(wrow + c);
      #pragma unroll
      for (int v = 0; v < 8; v++) {
        const float4 g4 = *reinterpret_cast<const float4*>(&a1[halfq*8+v][c]);
        acc[v] = fmaf(g4.x, w4.x, fmaf(g4.y, w4.y, fmaf(g4.z, w4.z, fmaf(g4.w, w4.w, acc[v]))));
      }
    }
    #pragma unroll
    for (int v = 0; v < 8; v++) hs[halfq*8+v][oc] = as[halfq*8+v][oc] + acc[v];
  }
  __syncthreads();
  { // out = relu(x @ fw.T + fb)
    const float* wrow = fw + (size_t)oc * CH;
    const float bia = fb[oc];
    float acc[8];
    #pragma unroll
    for (int v = 0; v < 8; v++) acc[v] = bia;
    for (int c = 0; c < CH; c += 4) {
      const float4 w4 = *reinterpret_cast<const float4*>(wrow + c);
      #pragma unroll
      for (int v = 0; v < 8; v++) {
        const float4 g4 = *reinterpret_cast<const float4*>(&hs[halfq*8+v][c]);
        acc[v] = fmaf(g4.x, w4.x, fmaf(g4.y, w4.y, fmaf(g4.z, w4.z, fmaf(g4.w, w4.w, acc[v]))));
      }
    }
    #pragma unroll
    for (int v = 0; v < 8; v++)
      outp[(size_t)(qbase + halfq*8 + v)*CH + oc] = fmaxf(acc[v], 0.0f);
  }
}

// ---------------------------------------------------------------------------
extern "C" void kernel_launch(void* const* d_in, const int* in_sizes, int n_in,
                              void* d_out, int out_size, void* d_ws, size_t ws_size,
                              hipStream_t stream) {
  const float* vfeat  = (const float*)d_in[0];
  const float* vcoord = (const float*)d_in[1];
  const float* qcoord = (const float*)d_in[2];
  const int*   kidx   = (const int*)  d_in[3];
  const float* n1g    = (const float*)d_in[4];
  const float* n1b    = (const float*)d_in[5];
  const float* qpw    = (const float*)d_in[6];
  const float* qpb    = (const float*)d_in[7];
  const float* kpw    = (const float*)d_in[8];
  const float* kpb    = (const float*)d_in[9];
  const float* in_w   = (const float*)d_in[10];
  const float* in_b   = (const float*)d_in[11];
  const float* out_w  = (const float*)d_in[12];
  const float* out_b  = (const float*)d_in[13];
  const float* n2g    = (const float*)d_in[14];
  const float* n2b    = (const float*)d_in[15];
  const float* l1w    = (const float*)d_in[16];
  const float* l1b    = (const float*)d_in[17];
  const float* l2w    = (const float*)d_in[18];
  const float* l2b    = (const float*)d_in[19];
  const float* fw     = (const float*)d_in[20];
  const float* fb     = (const float*)d_in[21];
  float* out = (float*)d_out;

  float* ws = (float*)d_ws;
  float* Kp  = ws;                               // 40000*128
  float* Vp  = Kp + (size_t)NVOX*CH;             // 40000*128
  float* qb  = Vp + (size_t)NVOX*CH;             // 8192*128
  float* cx  = qb + (size_t)NQRY*CH;             // 8192*128

  k_voxel<<<NVOX/8, 256, 0, stream>>>(vfeat, vcoord, n1g, n1b, kpw, kpb, in_w, in_b, Kp, Vp);
  k_query<<<NQRY/16, 256, 0, stream>>>(qcoord, qpw, qpb, in_w, in_b, qb);
  k_attn <<<NQRY,    256, 0, stream>>>(Kp, Vp, qb, kidx, cx);
  k_epi  <<<NQRY/16, 256, 0, stream>>>(cx, out_w, out_b, n2g, n2b, l1w, l1b, l2w, l2b, fw, fb, out);
}

// Round 2
// 327.287 us; speedup vs baseline: 1.0538x; 1.0538x over previous
//
#include <hip/hip_runtime.h>
#include <hip/hip_bf16.h>
#include <math.h>

// Problem constants (fixed by reference).
constexpr int NVOX = 40000;
constexpr int NQRY = 8192;
constexpr int KK   = 96;
constexpr int CH   = 128;
constexpr int FFD  = 256;

__device__ inline float bflo(unsigned u) { return __uint_as_float(u << 16); }
__device__ inline float bfhi(unsigned u) { return __uint_as_float(u & 0xffff0000u); }
__device__ inline unsigned short f2bf(float x) {
  union { float f; unsigned u; } a; a.f = x;
  const unsigned r = a.u + 0x7fffu + ((a.u >> 16) & 1u);  // round-to-nearest-even
  return (unsigned short)(r >> 16);
}

// ---------------------------------------------------------------------------
// Kernel 1: per-voxel — LayerNorm(voxel_features) + relu(coords@k_pos_w.T+b),
// then project through [wk;wv] (in_w rows 128..383) into bf16 Kp/Vp.
// 64 voxels per block of 256 threads; phase 2 is an 8x8 register-tiled GEMM
// (LDS bytes/FMA = 1 vs 4 in the broadcast-only version -> not LDS-bound).
// ---------------------------------------------------------------------------
__global__ __launch_bounds__(256) void k_voxel(
    const float* __restrict__ vfeat, const float* __restrict__ vcoord,
    const float* __restrict__ n1g, const float* __restrict__ n1b,
    const float* __restrict__ kpw, const float* __restrict__ kpb,
    const float* __restrict__ in_w, const float* __restrict__ in_b,
    __hip_bfloat16* __restrict__ Kp, __hip_bfloat16* __restrict__ Vp) {
  __shared__ float g[64][CH];   // 32 KB
  const int t = threadIdx.x;
  const int vbase = blockIdx.x * 64;
  {
    const int grp  = t >> 5;   // voxel within batch of 8
    const int lane = t & 31;   // channels lane*4 .. lane*4+3
    #pragma unroll
    for (int p = 0; p < 8; p++) {
      const int vloc = p * 8 + grp;
      const int j = vbase + vloc;
      const float4 x = reinterpret_cast<const float4*>(vfeat + (size_t)j * CH)[lane];
      float s  = x.x + x.y + x.z + x.w;
      float ss = x.x*x.x + x.y*x.y + x.z*x.z + x.w*x.w;
      #pragma unroll
      for (int m = 16; m >= 1; m >>= 1) { s += __shfl_xor(s, m); ss += __shfl_xor(ss, m); }
      const float mean = s * (1.0f/CH);
      const float var  = ss * (1.0f/CH) - mean*mean;
      const float rstd = 1.0f / sqrtf(var + 1e-5f);
      const float c0 = vcoord[j*3+0], c1 = vcoord[j*3+1], c2 = vcoord[j*3+2];
      const int cb = lane*4;
      const float xv[4] = {x.x, x.y, x.z, x.w};
      float4 gv;
      float* gp = &gv.x;
      #pragma unroll
      for (int u = 0; u < 4; u++) {
        const int c = cb + u;
        const float vf = (xv[u] - mean) * rstd * n1g[c] + n1b[c];
        float kp = fmaf(c0, kpw[c*3+0], fmaf(c1, kpw[c*3+1], fmaf(c2, kpw[c*3+2], kpb[c])));
        gp[u] = vf + fmaxf(kp, 0.0f);
      }
      *reinterpret_cast<float4*>(&g[vloc][cb]) = gv;
    }
  }
  __syncthreads();
  // Phase 2: 8x8 register-tiled GEMM. thread (tx,ty): out channels tx*8..+7
  // (0..255 across combined K|V), voxels ty*8..+7.
  const int tx = t & 31, ty = t >> 5;
  const int ch0 = tx * 8;
  const int v0  = ty * 8;
  const float* wbase = in_w + (size_t)(CH + ch0) * CH;
  float acc[8][8];
  #pragma unroll
  for (int v = 0; v < 8; v++)
    #pragma unroll
    for (int u = 0; u < 8; u++) acc[v][u] = 0.0f;
  for (int c = 0; c < CH; c += 4) {
    float4 wv[8];
    #pragma unroll
    for (int u = 0; u < 8; u++)
      wv[u] = *reinterpret_cast<const float4*>(wbase + (size_t)u*CH + c);
    float4 gv[8];
    #pragma unroll
    for (int v = 0; v < 8; v++)
      gv[v] = *reinterpret_cast<const float4*>(&g[v0+v][c]);   // broadcast (<=2 addr/wave)
    #pragma unroll
    for (int v = 0; v < 8; v++)
      #pragma unroll
      for (int u = 0; u < 8; u++)
        acc[v][u] = fmaf(gv[v].x, wv[u].x, fmaf(gv[v].y, wv[u].y,
                    fmaf(gv[v].z, wv[u].z, fmaf(gv[v].w, wv[u].w, acc[v][u]))));
  }
  float bia[8];
  #pragma unroll
  for (int u = 0; u < 8; u++) bia[u] = in_b[CH + ch0 + u];
  __hip_bfloat16* dst = (ch0 < CH) ? Kp : Vp;
  const int chd = ch0 & (CH-1);
  #pragma unroll
  for (int v = 0; v < 8; v++) {
    unsigned pk[4];
    #pragma unroll
    for (int u = 0; u < 4; u++) {
      const unsigned lo = f2bf(acc[v][2*u]   + bia[2*u]);
      const unsigned hi = f2bf(acc[v][2*u+1] + bia[2*u+1]);
      pk[u] = lo | (hi << 16);
    }
    *reinterpret_cast<uint4*>(dst + (size_t)(vbase + v0 + v)*CH + chd) =
        make_uint4(pk[0], pk[1], pk[2], pk[3]);
  }
}

// ---------------------------------------------------------------------------
// Kernel 2: per-query — q = relu(qc@q_pos_w.T + b) @ wq.T + bq (fp32).
// ---------------------------------------------------------------------------
__global__ __launch_bounds__(256) void k_query(
    const float* __restrict__ qcoord,
    const float* __restrict__ qpw, const float* __restrict__ qpb,
    const float* __restrict__ in_w, const float* __restrict__ in_b,
    float* __restrict__ qout) {
  __shared__ float qf[16][CH];
  const int t = threadIdx.x;
  const int qbase = blockIdx.x * 16;
  #pragma unroll
  for (int i = 0; i < 8; i++) {
    const int e = t + 256*i;
    const int qv = e >> 7, c = e & 127;
    const int qq = qbase + qv;
    const float v = fmaf(qcoord[qq*3+0], qpw[c*3+0],
                    fmaf(qcoord[qq*3+1], qpw[c*3+1],
                    fmaf(qcoord[qq*3+2], qpw[c*3+2], qpb[c])));
    qf[qv][c] = fmaxf(v, 0.0f);
  }
  __syncthreads();
  const int oc = t & 127, half = t >> 7;
  const float* wrow = in_w + (size_t)oc * CH;
  const float bia = in_b[oc];
  float acc[8];
  #pragma unroll
  for (int v = 0; v < 8; v++) acc[v] = bia;
  for (int c = 0; c < CH; c += 4) {
    const float4 w4 = *reinterpret_cast<const float4*>(wrow + c);
    #pragma unroll
    for (int v = 0; v < 8; v++) {
      const float4 g4 = *reinterpret_cast<const float4*>(&qf[half*8+v][c]);
      acc[v] = fmaf(g4.x, w4.x, fmaf(g4.y, w4.y, fmaf(g4.z, w4.z, fmaf(g4.w, w4.w, acc[v]))));
    }
  }
  #pragma unroll
  for (int v = 0; v < 8; v++) qout[(size_t)(qbase + half*8 + v)*CH + oc] = acc[v];
}

// ---------------------------------------------------------------------------
// Kernel 3: attention — one block per query, bf16 K/V gathers (half traffic).
// ---------------------------------------------------------------------------
__global__ __launch_bounds__(256) void k_attn(
    const __hip_bfloat16* __restrict__ Kp, const __hip_bfloat16* __restrict__ Vp,
    const float* __restrict__ qg, const int* __restrict__ kidx,
    float* __restrict__ ctxg) {
  __shared__ float qs[CH];
  __shared__ int   js[KK];
  __shared__ float sc[8*100];
  __shared__ float red[4][CH];
  __shared__ float rden[8];
  const int n = blockIdx.x;
  const int t = threadIdx.x;
  if (t < CH) qs[t] = qg[(size_t)n*CH + t];
  if (t < KK) js[t] = kidx[(size_t)n*KK + t];
  __syncthreads();
  // scores: 768 entries, 8 consecutive threads share one key row (256B coalesced)
  #pragma unroll
  for (int i = 0; i < 3; i++) {
    const int e = t + 256*i;
    const int k = e >> 3, h = e & 7;
    const int j = js[k];
    float s;
    if (j < 0) {
      s = -1e9f;
    } else {
      const uint4* kr = reinterpret_cast<const uint4*>(Kp + (size_t)j*CH + h*16);
      const uint4 ka = kr[0], kb = kr[1];
      const float* qh = qs + h*16;
      s = 0.0f;
      s = fmaf(qh[0],  bflo(ka.x), s); s = fmaf(qh[1],  bfhi(ka.x), s);
      s = fmaf(qh[2],  bflo(ka.y), s); s = fmaf(qh[3],  bfhi(ka.y), s);
      s = fmaf(qh[4],  bflo(ka.z), s); s = fmaf(qh[5],  bfhi(ka.z), s);
      s = fmaf(qh[6],  bflo(ka.w), s); s = fmaf(qh[7],  bfhi(ka.w), s);
      s = fmaf(qh[8],  bflo(kb.x), s); s = fmaf(qh[9],  bfhi(kb.x), s);
      s = fmaf(qh[10], bflo(kb.y), s); s = fmaf(qh[11], bfhi(kb.y), s);
      s = fmaf(qh[12], bflo(kb.z), s); s = fmaf(qh[13], bfhi(kb.z), s);
      s = fmaf(qh[14], bflo(kb.w), s); s = fmaf(qh[15], bfhi(kb.w), s);
      s *= 0.25f;   // 1/sqrt(16)
    }
    sc[h*100 + k] = s;
  }
  __syncthreads();
  // softmax per head: 16 lanes per head over 96 keys
  if (t < 128) {
    const int h = t >> 4, l = t & 15;
    float mx = -3e38f;
    for (int k = l; k < KK; k += 16) mx = fmaxf(mx, sc[h*100+k]);
    #pragma unroll
    for (int m = 8; m >= 1; m >>= 1) mx = fmaxf(mx, __shfl_xor(mx, m));
    float sum = 0.0f;
    for (int k = l; k < KK; k += 16) {
      const float p = __expf(sc[h*100+k] - mx);   // masked -> exactly 0
      sc[h*100+k] = p;
      sum += p;
    }
    #pragma unroll
    for (int m = 8; m >= 1; m >>= 1) sum += __shfl_xor(sum, m);
    if (l == 0) rden[h] = 1.0f / sum;
  }
  __syncthreads();
  // ctx: thread -> channel pair {2p,2p+1}; 4 groups x 24 keys
  {
    const int p = t & 63, grp = t >> 6;
    const int h = p >> 3;            // head of channel 2p (== head of 2p+1)
    float a0 = 0.0f, a1 = 0.0f;
    const int k0 = grp * 24;
    for (int k = k0; k < k0 + 24; k++) {
      const int j = js[k];           // wave-uniform branch
      if (j >= 0) {
        const unsigned vv = reinterpret_cast<const unsigned*>(Vp + (size_t)j*CH)[p];
        const float w = sc[h*100+k];
        a0 = fmaf(w, bflo(vv), a0);
        a1 = fmaf(w, bfhi(vv), a1);
      }
    }
    *reinterpret_cast<float2*>(&red[grp][2*p]) = make_float2(a0, a1);
  }
  __syncthreads();
  if (t < CH) {
    ctxg[(size_t)n*CH + t] =
        (red[0][t] + red[1][t] + red[2][t] + red[3][t]) * rden[t>>4];
  }
}

// ---------------------------------------------------------------------------
// Kernel 4: epilogue — attend = ctx@out_w.T+b; LN2; FFN; residual; final+relu.
// ---------------------------------------------------------------------------
__global__ __launch_bounds__(256) void k_epi(
    const float* __restrict__ ctxg,
    const float* __restrict__ ow, const float* __restrict__ ob,
    const float* __restrict__ n2g, const float* __restrict__ n2b,
    const float* __restrict__ l1w, const float* __restrict__ l1b,
    const float* __restrict__ l2w, const float* __restrict__ l2b,
    const float* __restrict__ fw, const float* __restrict__ fb,
    float* __restrict__ outp) {
  __shared__ float cs[16][CH];
  __shared__ float as[16][132];
  __shared__ float hs[16][132];
  __shared__ float a1[16][FFD];
  const int t = threadIdx.x;
  const int qbase = blockIdx.x * 16;
  #pragma unroll
  for (int i = 0; i < 8; i++) {
    const int e = t + 256*i;
    const int qv = e >> 7, c = e & 127;
    cs[qv][c] = ctxg[(size_t)(qbase+qv)*CH + c];
  }
  __syncthreads();
  const int oc = t & 127, halfq = t >> 7;
  { // attend = cs @ ow.T + ob
    const float* wrow = ow + (size_t)oc * CH;
    const float bia = ob[oc];
    float acc[8];
    #pragma unroll
    for (int v = 0; v < 8; v++) acc[v] = bia;
    for (int c = 0; c < CH; c += 4) {
      const float4 w4 = *reinterpret_cast<const float4*>(wrow + c);
      #pragma unroll
      for (int v = 0; v < 8; v++) {
        const float4 g4 = *reinterpret_cast<const float4*>(&cs[halfq*8+v][c]);
        acc[v] = fmaf(g4.x, w4.x, fmaf(g4.y, w4.y, fmaf(g4.z, w4.z, fmaf(g4.w, w4.w, acc[v]))));
      }
    }
    #pragma unroll
    for (int v = 0; v < 8; v++) as[halfq*8+v][oc] = acc[v];
  }
  __syncthreads();
  { // LayerNorm2
    const int row = t >> 4, l = t & 15;
    float s = 0.0f, ss = 0.0f;
    for (int c = l; c < CH; c += 16) { const float x = as[row][c]; s += x; ss += x*x; }
    #pragma unroll
    for (int m = 8; m >= 1; m >>= 1) { s += __shfl_xor(s, m); ss += __shfl_xor(ss, m); }
    const float mean = s * (1.0f/CH);
    const float var  = ss * (1.0f/CH) - mean*mean;
    const float rstd = 1.0f / sqrtf(var + 1e-5f);
    for (int c = l; c < CH; c += 16)
      hs[row][c] = (as[row][c] - mean) * rstd * n2g[c] + n2b[c];
  }
  __syncthreads();
  { // act1 = relu(hs @ l1w.T + l1b)
    const float* wrow = l1w + (size_t)t * CH;
    const float bia = l1b[t];
    float acc[16];
    #pragma unroll
    for (int v = 0; v < 16; v++) acc[v] = bia;
    for (int c = 0; c < CH; c += 4) {
      const float4 w4 = *reinterpret_cast<const float4*>(wrow + c);
      #pragma unroll
      for (int v = 0; v < 16; v++) {
        const float4 g4 = *reinterpret_cast<const float4*>(&hs[v][c]);
        acc[v] = fmaf(g4.x, w4.x, fmaf(g4.y, w4.y, fmaf(g4.z, w4.z, fmaf(g4.w, w4.w, acc[v]))));
      }
    }
    #pragma unroll
    for (int v = 0; v < 16; v++) a1[v][t] = fmaxf(acc[v], 0.0f);
  }
  __syncthreads();
  { // x = attend + a1 @ l2w.T + l2b -> hs
    const float* wrow = l2w + (size_t)oc * FFD;
    const float bia = l2b[oc];
    float acc[8];
    #pragma unroll
    for (int v = 0; v < 8; v++) acc[v] = bia;
    for (int c = 0; c < FFD; c += 4) {
      const float4 w4 = *reinterpret_cast<const float4*>(wrow + c);
      #pragma unroll
      for (int v = 0; v < 8; v++) {
        const float4 g4 = *reinterpret_cast<const float4*>(&a1[halfq*8+v][c]);
        acc[v] = fmaf(g4.x, w4.x, fmaf(g4.y, w4.y, fmaf(g4.z, w4.z, fmaf(g4.w, w4.w, acc[v]))));
      }
    }
    #pragma unroll
    for (int v = 0; v < 8; v++) hs[halfq*8+v][oc] = as[halfq*8+v][oc] + acc[v];
  }
  __syncthreads();
  { // out = relu(x @ fw.T + fb)
    const float* wrow = fw + (size_t)oc * CH;
    const float bia = fb[oc];
    float acc[8];
    #pragma unroll
    for (int v = 0; v < 8; v++) acc[v] = bia;
    for (int c = 0; c < CH; c += 4) {
      const float4 w4 = *reinterpret_cast<const float4*>(wrow + c);
      #pragma unroll
      for (int v = 0; v < 8; v++) {
        const float4 g4 = *reinterpret_cast<const float4*>(&hs[halfq*8+v][c]);
        acc[v] = fmaf(g4.x, w4.x, fmaf(g4.y, w4.y, fmaf(g4.z, w4.z, fmaf(g4.w, w4.w, acc[v]))));
      }
    }
    #pragma unroll
    for (int v = 0; v < 8; v++)
      outp[(size_t)(qbase + halfq*8 + v)*CH + oc] = fmaxf(acc[v], 0.0f);
  }
}

// ---------------------------------------------------------------------------
extern "C" void kernel_launch(void* const* d_in, const int* in_sizes, int n_in,
                              void* d_out, int out_size, void* d_ws, size_t ws_size,
                              hipStream_t stream) {
  const float* vfeat  = (const float*)d_in[0];
  const float* vcoord = (const float*)d_in[1];
  const float* qcoord = (const float*)d_in[2];
  const int*   kidx   = (const int*)  d_in[3];
  const float* n1g    = (const float*)d_in[4];
  const float* n1b    = (const float*)d_in[5];
  const float* qpw    = (const float*)d_in[6];
  const float* qpb    = (const float*)d_in[7];
  const float* kpw    = (const float*)d_in[8];
  const float* kpb    = (const float*)d_in[9];
  const float* in_w   = (const float*)d_in[10];
  const float* in_b   = (const float*)d_in[11];
  const float* out_w  = (const float*)d_in[12];
  const float* out_b  = (const float*)d_in[13];
  const float* n2g    = (const float*)d_in[14];
  const float* n2b    = (const float*)d_in[15];
  const float* l1w    = (const float*)d_in[16];
  const float* l1b    = (const float*)d_in[17];
  const float* l2w    = (const float*)d_in[18];
  const float* l2b    = (const float*)d_in[19];
  const float* fw     = (const float*)d_in[20];
  const float* fb     = (const float*)d_in[21];
  float* out = (float*)d_out;

  __hip_bfloat16* Kp = (__hip_bfloat16*)d_ws;          // NVOX*CH bf16
  __hip_bfloat16* Vp = Kp + (size_t)NVOX*CH;           // NVOX*CH bf16
  float* qb = (float*)(Vp + (size_t)NVOX*CH);          // NQRY*CH f32
  float* cx = qb + (size_t)NQRY*CH;                    // NQRY*CH f32

  k_voxel<<<NVOX/64, 256, 0, stream>>>(vfeat, vcoord, n1g, n1b, kpw, kpb, in_w, in_b, Kp, Vp);
  k_query<<<NQRY/16, 256, 0, stream>>>(qcoord, qpw, qpb, in_w, in_b, qb);
  k_attn <<<NQRY,    256, 0, stream>>>(Kp, Vp, qb, kidx, cx);
  k_epi  <<<NQRY/16, 256, 0, stream>>>(cx, out_w, out_b, n2g, n2b, l1w, l1b, l2w, l2b, fw, fb, out);
}

// Round 3
// 252.516 us; speedup vs baseline: 1.3658x; 1.2961x over previous
//
#include <hip/hip_runtime.h>
#include <hip/hip_bf16.h>
#include <math.h>

// Problem constants (fixed by reference).
constexpr int NVOX = 40000;
constexpr int NQRY = 8192;
constexpr int KK   = 96;
constexpr int CH   = 128;
constexpr int FFD  = 256;

typedef __attribute__((ext_vector_type(8))) short short8;
typedef __attribute__((ext_vector_type(4))) float float4v;

__device__ inline float bflo(unsigned u) { return __uint_as_float(u << 16); }
__device__ inline float bfhi(unsigned u) { return __uint_as_float(u & 0xffff0000u); }
__device__ inline unsigned short f2bf(float x) {
  union { float f; unsigned u; } a; a.f = x;
  const unsigned r = a.u + 0x7fffu + ((a.u >> 16) & 1u);  // round-to-nearest-even
  return (unsigned short)(r >> 16);
}
__device__ inline unsigned pack2(float lo, float hi) {
  return (unsigned)f2bf(lo) | ((unsigned)f2bf(hi) << 16);
}

// ---------------------------------------------------------------------------
// Kernel 1: prep — (a) per-voxel LN + relu(key-pos) -> Gb bf16 [NVOX][128];
// (b) convert Wkv (in_w rows 128..383) -> Wb bf16 [256][128].
// Blocks 0..2499: 16 voxels each (16 lanes/voxel). Blocks 2500..2507: Wkv.
// ---------------------------------------------------------------------------
__global__ __launch_bounds__(256) void k_prep(
    const float* __restrict__ vfeat, const float* __restrict__ vcoord,
    const float* __restrict__ n1g, const float* __restrict__ n1b,
    const float* __restrict__ kpw, const float* __restrict__ kpb,
    const float* __restrict__ in_w,
    __hip_bfloat16* __restrict__ Gb, __hip_bfloat16* __restrict__ Wb) {
  const int b = blockIdx.x;
  const int t = threadIdx.x;
  if (b < NVOX/16) {
    const int vloc = t >> 4;     // voxel within block
    const int l    = t & 15;     // 16 lanes per voxel; lane -> channels l*8..+7
    const int j = b * 16 + vloc;
    const float4* vrow = reinterpret_cast<const float4*>(vfeat + (size_t)j * CH);
    const float4 x0 = vrow[l*2], x1 = vrow[l*2+1];
    float s  = x0.x+x0.y+x0.z+x0.w + x1.x+x1.y+x1.z+x1.w;
    float ss = x0.x*x0.x+x0.y*x0.y+x0.z*x0.z+x0.w*x0.w
             + x1.x*x1.x+x1.y*x1.y+x1.z*x1.z+x1.w*x1.w;
    #pragma unroll
    for (int m = 8; m >= 1; m >>= 1) { s += __shfl_xor(s, m); ss += __shfl_xor(ss, m); }
    const float mean = s * (1.0f/CH);
    const float var  = ss * (1.0f/CH) - mean*mean;
    const float rstd = 1.0f / sqrtf(var + 1e-5f);
    const float c0 = vcoord[j*3+0], c1 = vcoord[j*3+1], c2 = vcoord[j*3+2];
    const float xv[8] = {x0.x,x0.y,x0.z,x0.w,x1.x,x1.y,x1.z,x1.w};
    float gv[8];
    #pragma unroll
    for (int u = 0; u < 8; u++) {
      const int c = l*8 + u;
      const float vf = (xv[u] - mean) * rstd * n1g[c] + n1b[c];
      const float kp = fmaf(c0, kpw[c*3+0], fmaf(c1, kpw[c*3+1], fmaf(c2, kpw[c*3+2], kpb[c])));
      gv[u] = vf + fmaxf(kp, 0.0f);
    }
    const uint4 pk = make_uint4(pack2(gv[0],gv[1]), pack2(gv[2],gv[3]),
                                pack2(gv[4],gv[5]), pack2(gv[6],gv[7]));
    *reinterpret_cast<uint4*>(Gb + (size_t)j*CH + l*8) = pk;
  } else {
    // Wkv conversion: 8 blocks x 256 threads x 16 elems = 256*128.
    const int e = ((b - NVOX/16) * 256 + t) * 16;
    const float* src = in_w + (size_t)CH*CH + e;   // rows 128.. of in_w
    float v[16];
    #pragma unroll
    for (int u = 0; u < 4; u++) {
      const float4 f = *reinterpret_cast<const float4*>(src + u*4);
      v[u*4+0]=f.x; v[u*4+1]=f.y; v[u*4+2]=f.z; v[u*4+3]=f.w;
    }
    uint4 o0 = make_uint4(pack2(v[0],v[1]), pack2(v[2],v[3]),
                          pack2(v[4],v[5]), pack2(v[6],v[7]));
    uint4 o1 = make_uint4(pack2(v[8],v[9]), pack2(v[10],v[11]),
                          pack2(v[12],v[13]), pack2(v[14],v[15]));
    uint4* dst = reinterpret_cast<uint4*>(Wb + e);
    dst[0] = o0; dst[1] = o1;
  }
}

// ---------------------------------------------------------------------------
// Kernel 1b: KV projection GEMM via MFMA bf16.
// D[vox][oc] = Gb[vox][:] . Wb[oc][:] + bias[oc], oc in [0,256) = [wk;wv].
// Block: 256 thr = 4 waves; tile 64 vox x 64 ch. Wave w: voxels w*16..+15.
// Grid: (NVOX/64) * 4 channel-groups = 2500 blocks.
// Layouts (guide-verified): A[m=lane&15][k=quad*8+j]; B[k=quad*8+j][n=lane&15];
// D col=lane&15 (ch), row=quad*4+reg (vox).
// ---------------------------------------------------------------------------
__global__ __launch_bounds__(256) void k_kv_gemm(
    const __hip_bfloat16* __restrict__ Gb, const __hip_bfloat16* __restrict__ Wb,
    const float* __restrict__ in_b,
    __hip_bfloat16* __restrict__ Kp, __hip_bfloat16* __restrict__ Vp) {
  __shared__ unsigned short ldsD[64][72];   // pad 72: 16B-aligned rows (144 B)
  const int t = threadIdx.x;
  const int w = t >> 6;
  const int lane = t & 63;
  const int col = lane & 15;
  const int quad = lane >> 4;
  const int bx = blockIdx.x;
  const int v0 = (bx >> 2) * 64;
  const int cg = bx & 3;                    // channel group (64 ch of 256)

  const unsigned short* gRow =
      reinterpret_cast<const unsigned short*>(Gb) + (size_t)(v0 + w*16 + col)*CH + quad*8;
  short8 afrag[4];
  #pragma unroll
  for (int kq = 0; kq < 4; kq++)
    afrag[kq] = *reinterpret_cast<const short8*>(gRow + kq*32);

  float4v acc[4];
  #pragma unroll
  for (int j = 0; j < 4; j++) {
    const float bia = in_b[CH + cg*64 + j*16 + col];
    acc[j] = (float4v){bia, bia, bia, bia};
  }
  const unsigned short* wB = reinterpret_cast<const unsigned short*>(Wb);
  #pragma unroll
  for (int kq = 0; kq < 4; kq++) {
    #pragma unroll
    for (int j = 0; j < 4; j++) {
      const short8 bfrag = *reinterpret_cast<const short8*>(
          wB + (size_t)(cg*64 + j*16 + col)*CH + kq*32 + quad*8);
      acc[j] = __builtin_amdgcn_mfma_f32_16x16x32_bf16(afrag[kq], bfrag, acc[j], 0, 0, 0);
    }
  }
  #pragma unroll
  for (int j = 0; j < 4; j++)
    #pragma unroll
    for (int r = 0; r < 4; r++)
      ldsD[w*16 + quad*4 + r][j*16 + col] = f2bf(acc[j][r]);
  __syncthreads();
  // Coalesced writeout: thread -> (row=t>>2, 16-ch chunk), 32 B per thread.
  const int row = t >> 2;
  const int cc  = (t & 3) * 16;
  const uint4 d0 = *reinterpret_cast<const uint4*>(&ldsD[row][cc]);
  const uint4 d1 = *reinterpret_cast<const uint4*>(&ldsD[row][cc+8]);
  __hip_bfloat16* dst = (cg < 2) ? Kp : Vp;
  uint4* out = reinterpret_cast<uint4*>(dst + (size_t)(v0 + row)*CH + (cg & 1)*64 + cc);
  out[0] = d0; out[1] = d1;
}

// ---------------------------------------------------------------------------
// Kernel 2: per-query — q = relu(qc@q_pos_w.T + b) @ wq.T + bq (fp32).
// ---------------------------------------------------------------------------
__global__ __launch_bounds__(256) void k_query(
    const float* __restrict__ qcoord,
    const float* __restrict__ qpw, const float* __restrict__ qpb,
    const float* __restrict__ in_w, const float* __restrict__ in_b,
    float* __restrict__ qout) {
  __shared__ float qf[16][CH];
  const int t = threadIdx.x;
  const int qbase = blockIdx.x * 16;
  #pragma unroll
  for (int i = 0; i < 8; i++) {
    const int e = t + 256*i;
    const int qv = e >> 7, c = e & 127;
    const int qq = qbase + qv;
    const float v = fmaf(qcoord[qq*3+0], qpw[c*3+0],
                    fmaf(qcoord[qq*3+1], qpw[c*3+1],
                    fmaf(qcoord[qq*3+2], qpw[c*3+2], qpb[c])));
    qf[qv][c] = fmaxf(v, 0.0f);
  }
  __syncthreads();
  const int oc = t & 127, half = t >> 7;
  const float* wrow = in_w + (size_t)oc * CH;
  const float bia = in_b[oc];
  float acc[8];
  #pragma unroll
  for (int v = 0; v < 8; v++) acc[v] = bia;
  for (int c = 0; c < CH; c += 4) {
    const float4 w4 = *reinterpret_cast<const float4*>(wrow + c);
    #pragma unroll
    for (int v = 0; v < 8; v++) {
      const float4 g4 = *reinterpret_cast<const float4*>(&qf[half*8+v][c]);
      acc[v] = fmaf(g4.x, w4.x, fmaf(g4.y, w4.y, fmaf(g4.z, w4.z, fmaf(g4.w, w4.w, acc[v]))));
    }
  }
  #pragma unroll
  for (int v = 0; v < 8; v++) qout[(size_t)(qbase + half*8 + v)*CH + oc] = acc[v];
}

// ---------------------------------------------------------------------------
// Kernel 3: attention — one block per query, bf16 K/V gathers.
// ---------------------------------------------------------------------------
__global__ __launch_bounds__(256) void k_attn(
    const __hip_bfloat16* __restrict__ Kp, const __hip_bfloat16* __restrict__ Vp,
    const float* __restrict__ qg, const int* __restrict__ kidx,
    float* __restrict__ ctxg) {
  __shared__ float qs[CH];
  __shared__ int   js[KK];
  __shared__ float sc[8*100];
  __shared__ float red[4][CH];
  __shared__ float rden[8];
  const int n = blockIdx.x;
  const int t = threadIdx.x;
  if (t < CH) qs[t] = qg[(size_t)n*CH + t];
  if (t < KK) js[t] = kidx[(size_t)n*KK + t];
  __syncthreads();
  #pragma unroll
  for (int i = 0; i < 3; i++) {
    const int e = t + 256*i;
    const int k = e >> 3, h = e & 7;
    const int j = js[k];
    float s;
    if (j < 0) {
      s = -1e9f;
    } else {
      const uint4* kr = reinterpret_cast<const uint4*>(Kp + (size_t)j*CH + h*16);
      const uint4 ka = kr[0], kb = kr[1];
      const float* qh = qs + h*16;
      s = 0.0f;
      s = fmaf(qh[0],  bflo(ka.x), s); s = fmaf(qh[1],  bfhi(ka.x), s);
      s = fmaf(qh[2],  bflo(ka.y), s); s = fmaf(qh[3],  bfhi(ka.y), s);
      s = fmaf(qh[4],  bflo(ka.z), s); s = fmaf(qh[5],  bfhi(ka.z), s);
      s = fmaf(qh[6],  bflo(ka.w), s); s = fmaf(qh[7],  bfhi(ka.w), s);
      s = fmaf(qh[8],  bflo(kb.x), s); s = fmaf(qh[9],  bfhi(kb.x), s);
      s = fmaf(qh[10], bflo(kb.y), s); s = fmaf(qh[11], bfhi(kb.y), s);
      s = fmaf(qh[12], bflo(kb.z), s); s = fmaf(qh[13], bfhi(kb.z), s);
      s = fmaf(qh[14], bflo(kb.w), s); s = fmaf(qh[15], bfhi(kb.w), s);
      s *= 0.25f;   // 1/sqrt(16)
    }
    sc[h*100 + k] = s;
  }
  __syncthreads();
  if (t < 128) {
    const int h = t >> 4, l = t & 15;
    float mx = -3e38f;
    for (int k = l; k < KK; k += 16) mx = fmaxf(mx, sc[h*100+k]);
    #pragma unroll
    for (int m = 8; m >= 1; m >>= 1) mx = fmaxf(mx, __shfl_xor(mx, m));
    float sum = 0.0f;
    for (int k = l; k < KK; k += 16) {
      const float p = __expf(sc[h*100+k] - mx);   // masked -> exactly 0
      sc[h*100+k] = p;
      sum += p;
    }
    #pragma unroll
    for (int m = 8; m >= 1; m >>= 1) sum += __shfl_xor(sum, m);
    if (l == 0) rden[h] = 1.0f / sum;
  }
  __syncthreads();
  {
    const int p = t & 63, grp = t >> 6;
    const int h = p >> 3;
    float a0 = 0.0f, a1 = 0.0f;
    const int k0 = grp * 24;
    for (int k = k0; k < k0 + 24; k++) {
      const int j = js[k];           // wave-uniform branch
      if (j >= 0) {
        const unsigned vv = reinterpret_cast<const unsigned*>(Vp + (size_t)j*CH)[p];
        const float w = sc[h*100+k];
        a0 = fmaf(w, bflo(vv), a0);
        a1 = fmaf(w, bfhi(vv), a1);
      }
    }
    *reinterpret_cast<float2*>(&red[grp][2*p]) = make_float2(a0, a1);
  }
  __syncthreads();
  if (t < CH) {
    ctxg[(size_t)n*CH + t] =
        (red[0][t] + red[1][t] + red[2][t] + red[3][t]) * rden[t>>4];
  }
}

// ---------------------------------------------------------------------------
// Kernel 4: epilogue — attend = ctx@out_w.T+b; LN2; FFN; residual; final+relu.
// ---------------------------------------------------------------------------
__global__ __launch_bounds__(256) void k_epi(
    const float* __restrict__ ctxg,
    const float* __restrict__ ow, const float* __restrict__ ob,
    const float* __restrict__ n2g, const float* __restrict__ n2b,
    const float* __restrict__ l1w, const float* __restrict__ l1b,
    const float* __restrict__ l2w, const float* __restrict__ l2b,
    const float* __restrict__ fw, const float* __restrict__ fb,
    float* __restrict__ outp) {
  __shared__ float cs[16][CH];
  __shared__ float as[16][132];
  __shared__ float hs[16][132];
  __shared__ float a1[16][FFD];
  const int t = threadIdx.x;
  const int qbase = blockIdx.x * 16;
  #pragma unroll
  for (int i = 0; i < 8; i++) {
    const int e = t + 256*i;
    const int qv = e >> 7, c = e & 127;
    cs[qv][c] = ctxg[(size_t)(qbase+qv)*CH + c];
  }
  __syncthreads();
  const int oc = t & 127, halfq = t >> 7;
  { // attend = cs @ ow.T + ob
    const float* wrow = ow + (size_t)oc * CH;
    const float bia = ob[oc];
    float acc[8];
    #pragma unroll
    for (int v = 0; v < 8; v++) acc[v] = bia;
    for (int c = 0; c < CH; c += 4) {
      const float4 w4 = *reinterpret_cast<const float4*>(wrow + c);
      #pragma unroll
      for (int v = 0; v < 8; v++) {
        const float4 g4 = *reinterpret_cast<const float4*>(&cs[halfq*8+v][c]);
        acc[v] = fmaf(g4.x, w4.x, fmaf(g4.y, w4.y, fmaf(g4.z, w4.z, fmaf(g4.w, w4.w, acc[v]))));
      }
    }
    #pragma unroll
    for (int v = 0; v < 8; v++) as[halfq*8+v][oc] = acc[v];
  }
  __syncthreads();
  { // LayerNorm2
    const int row = t >> 4, l = t & 15;
    float s = 0.0f, ss = 0.0f;
    for (int c = l; c < CH; c += 16) { const float x = as[row][c]; s += x; ss += x*x; }
    #pragma unroll
    for (int m = 8; m >= 1; m >>= 1) { s += __shfl_xor(s, m); ss += __shfl_xor(ss, m); }
    const float mean = s * (1.0f/CH);
    const float var  = ss * (1.0f/CH) - mean*mean;
    const float rstd = 1.0f / sqrtf(var + 1e-5f);
    for (int c = l; c < CH; c += 16)
      hs[row][c] = (as[row][c] - mean) * rstd * n2g[c] + n2b[c];
  }
  __syncthreads();
  { // act1 = relu(hs @ l1w.T + l1b)
    const float* wrow = l1w + (size_t)t * CH;
    const float bia = l1b[t];
    float acc[16];
    #pragma unroll
    for (int v = 0; v < 16; v++) acc[v] = bia;
    for (int c = 0; c < CH; c += 4) {
      const float4 w4 = *reinterpret_cast<const float4*>(wrow + c);
      #pragma unroll
      for (int v = 0; v < 16; v++) {
        const float4 g4 = *reinterpret_cast<const float4*>(&hs[v][c]);
        acc[v] = fmaf(g4.x, w4.x, fmaf(g4.y, w4.y, fmaf(g4.z, w4.z, fmaf(g4.w, w4.w, acc[v]))));
      }
    }
    #pragma unroll
    for (int v = 0; v < 16; v++) a1[v][t] = fmaxf(acc[v], 0.0f);
  }
  __syncthreads();
  { // x = attend + a1 @ l2w.T + l2b -> hs
    const float* wrow = l2w + (size_t)oc * FFD;
    const float bia = l2b[oc];
    float acc[8];
    #pragma unroll
    for (int v = 0; v < 8; v++) acc[v] = bia;
    for (int c = 0; c < FFD; c += 4) {
      const float4 w4 = *reinterpret_cast<const float4*>(wrow + c);
      #pragma unroll
      for (int v = 0; v < 8; v++) {
        const float4 g4 = *reinterpret_cast<const float4*>(&a1[halfq*8+v][c]);
        acc[v] = fmaf(g4.x, w4.x, fmaf(g4.y, w4.y, fmaf(g4.z, w4.z, fmaf(g4.w, w4.w, acc[v]))));
      }
    }
    #pragma unroll
    for (int v = 0; v < 8; v++) hs[halfq*8+v][oc] = as[halfq*8+v][oc] + acc[v];
  }
  __syncthreads();
  { // out = relu(x @ fw.T + fb)
    const float* wrow = fw + (size_t)oc * CH;
    const float bia = fb[oc];
    float acc[8];
    #pragma unroll
    for (int v = 0; v < 8; v++) acc[v] = bia;
    for (int c = 0; c < CH; c += 4) {
      const float4 w4 = *reinterpret_cast<const float4*>(wrow + c);
      #pragma unroll
      for (int v = 0; v < 8; v++) {
        const float4 g4 = *reinterpret_cast<const float4*>(&hs[halfq*8+v][c]);
        acc[v] = fmaf(g4.x, w4.x, fmaf(g4.y, w4.y, fmaf(g4.z, w4.z, fmaf(g4.w, w4.w, acc[v]))));
      }
    }
    #pragma unroll
    for (int v = 0; v < 8; v++)
      outp[(size_t)(qbase + halfq*8 + v)*CH + oc] = fmaxf(acc[v], 0.0f);
  }
}

// ---------------------------------------------------------------------------
extern "C" void kernel_launch(void* const* d_in, const int* in_sizes, int n_in,
                              void* d_out, int out_size, void* d_ws, size_t ws_size,
                              hipStream_t stream) {
  const float* vfeat  = (const float*)d_in[0];
  const float* vcoord = (const float*)d_in[1];
  const float* qcoord = (const float*)d_in[2];
  const int*   kidx   = (const int*)  d_in[3];
  const float* n1g    = (const float*)d_in[4];
  const float* n1b    = (const float*)d_in[5];
  const float* qpw    = (const float*)d_in[6];
  const float* qpb    = (const float*)d_in[7];
  const float* kpw    = (const float*)d_in[8];
  const float* kpb    = (const float*)d_in[9];
  const float* in_w   = (const float*)d_in[10];
  const float* in_b   = (const float*)d_in[11];
  const float* out_w  = (const float*)d_in[12];
  const float* out_b  = (const float*)d_in[13];
  const float* n2g    = (const float*)d_in[14];
  const float* n2b    = (const float*)d_in[15];
  const float* l1w    = (const float*)d_in[16];
  const float* l1b    = (const float*)d_in[17];
  const float* l2w    = (const float*)d_in[18];
  const float* l2b    = (const float*)d_in[19];
  const float* fw     = (const float*)d_in[20];
  const float* fb     = (const float*)d_in[21];
  float* out = (float*)d_out;

  __hip_bfloat16* Kp = (__hip_bfloat16*)d_ws;          // NVOX*CH bf16
  __hip_bfloat16* Vp = Kp + (size_t)NVOX*CH;           // NVOX*CH bf16
  __hip_bfloat16* Gb = Vp + (size_t)NVOX*CH;           // NVOX*CH bf16
  __hip_bfloat16* Wb = Gb + (size_t)NVOX*CH;           // 256*CH bf16
  float* qb = (float*)(Wb + (size_t)2*CH*CH);          // NQRY*CH f32
  float* cx = qb + (size_t)NQRY*CH;                    // NQRY*CH f32

  k_prep   <<<NVOX/16 + 8, 256, 0, stream>>>(vfeat, vcoord, n1g, n1b, kpw, kpb, in_w, Gb, Wb);
  k_query  <<<NQRY/16, 256, 0, stream>>>(qcoord, qpw, qpb, in_w, in_b, qb);
  k_kv_gemm<<<(NVOX/64)*4, 256, 0, stream>>>(Gb, Wb, in_b, Kp, Vp);
  k_attn   <<<NQRY,    256, 0, stream>>>(Kp, Vp, qb, kidx, cx);
  k_epi    <<<NQRY/16, 256, 0, stream>>>(cx, out_w, out_b, n2g, n2b, l1w, l1b, l2w, l2b, fw, fb, out);
}

// Round 4
// 219.473 us; speedup vs baseline: 1.5714x; 1.1506x over previous
//
#include <hip/hip_runtime.h>
#include <hip/hip_bf16.h>
#include <math.h>

// Problem constants (fixed by reference).
constexpr int NVOX = 40000;
constexpr int NQRY = 8192;
constexpr int KK   = 96;
constexpr int CH   = 128;
constexpr int FFD  = 256;

typedef __attribute__((ext_vector_type(8))) short short8;
typedef __attribute__((ext_vector_type(4))) float float4v;

__device__ inline float bflo(unsigned u) { return __uint_as_float(u << 16); }
__device__ inline float bfhi(unsigned u) { return __uint_as_float(u & 0xffff0000u); }
__device__ inline unsigned short f2bf(float x) {
  union { float f; unsigned u; } a; a.f = x;
  const unsigned r = a.u + 0x7fffu + ((a.u >> 16) & 1u);  // round-to-nearest-even
  return (unsigned short)(r >> 16);
}
__device__ inline unsigned pack2(float lo, float hi) {
  return (unsigned)f2bf(lo) | ((unsigned)f2bf(hi) << 16);
}

// ---------------------------------------------------------------------------
// Kernel 1: prep — (a) per-voxel LN + relu(key-pos) -> Gb bf16 [NVOX][128];
// (b) convert Wkv (in_w rows 128..383) -> Wb bf16; (c) convert the 4 epilogue
// weight matrices (out_w,l1w,l2w,fw; 98304 floats) -> Eb bf16.
// ---------------------------------------------------------------------------
__global__ __launch_bounds__(256) void k_prep(
    const float* __restrict__ vfeat, const float* __restrict__ vcoord,
    const float* __restrict__ n1g, const float* __restrict__ n1b,
    const float* __restrict__ kpw, const float* __restrict__ kpb,
    const float* __restrict__ in_w,
    const float* __restrict__ ow, const float* __restrict__ l1w,
    const float* __restrict__ l2w, const float* __restrict__ fw,
    __hip_bfloat16* __restrict__ Gb, __hip_bfloat16* __restrict__ Wb,
    __hip_bfloat16* __restrict__ Eb) {
  const int b = blockIdx.x;
  const int t = threadIdx.x;
  if (b < NVOX/16) {
    const int vloc = t >> 4;     // voxel within block
    const int l    = t & 15;     // lane -> channels l*8..+7
    const int j = b * 16 + vloc;
    const float4* vrow = reinterpret_cast<const float4*>(vfeat + (size_t)j * CH);
    const float4 x0 = vrow[l*2], x1 = vrow[l*2+1];
    float s  = x0.x+x0.y+x0.z+x0.w + x1.x+x1.y+x1.z+x1.w;
    float ss = x0.x*x0.x+x0.y*x0.y+x0.z*x0.z+x0.w*x0.w
             + x1.x*x1.x+x1.y*x1.y+x1.z*x1.z+x1.w*x1.w;
    #pragma unroll
    for (int m = 8; m >= 1; m >>= 1) { s += __shfl_xor(s, m); ss += __shfl_xor(ss, m); }
    const float mean = s * (1.0f/CH);
    const float var  = ss * (1.0f/CH) - mean*mean;
    const float rstd = 1.0f / sqrtf(var + 1e-5f);
    const float c0 = vcoord[j*3+0], c1 = vcoord[j*3+1], c2 = vcoord[j*3+2];
    const float xv[8] = {x0.x,x0.y,x0.z,x0.w,x1.x,x1.y,x1.z,x1.w};
    float gv[8];
    #pragma unroll
    for (int u = 0; u < 8; u++) {
      const int c = l*8 + u;
      const float vf = (xv[u] - mean) * rstd * n1g[c] + n1b[c];
      const float kp = fmaf(c0, kpw[c*3+0], fmaf(c1, kpw[c*3+1], fmaf(c2, kpw[c*3+2], kpb[c])));
      gv[u] = vf + fmaxf(kp, 0.0f);
    }
    const uint4 pk = make_uint4(pack2(gv[0],gv[1]), pack2(gv[2],gv[3]),
                                pack2(gv[4],gv[5]), pack2(gv[6],gv[7]));
    *reinterpret_cast<uint4*>(Gb + (size_t)j*CH + l*8) = pk;
  } else {
    const int idx = b - NVOX/16;
    const float* src;
    __hip_bfloat16* dst;
    if (idx < 8) {
      const int e = (idx * 256 + t) * 16;
      src = in_w + (size_t)CH*CH + e;   // Wkv rows 128.. of in_w
      dst = Wb + e;
    } else {
      const int f = ((idx - 8) * 256 + t) * 16;   // 0..98303
      dst = Eb + f;
      if      (f < 16384) src = ow  + f;
      else if (f < 49152) src = l1w + (f - 16384);
      else if (f < 81920) src = l2w + (f - 49152);
      else                src = fw  + (f - 81920);
    }
    float v[16];
    #pragma unroll
    for (int u = 0; u < 4; u++) {
      const float4 fq = *reinterpret_cast<const float4*>(src + u*4);
      v[u*4+0]=fq.x; v[u*4+1]=fq.y; v[u*4+2]=fq.z; v[u*4+3]=fq.w;
    }
    uint4* o = reinterpret_cast<uint4*>(dst);
    o[0] = make_uint4(pack2(v[0],v[1]), pack2(v[2],v[3]),
                      pack2(v[4],v[5]), pack2(v[6],v[7]));
    o[1] = make_uint4(pack2(v[8],v[9]), pack2(v[10],v[11]),
                      pack2(v[12],v[13]), pack2(v[14],v[15]));
  }
}

// ---------------------------------------------------------------------------
// Kernel 1b: KV projection GEMM via MFMA bf16 (unchanged from round 3).
// ---------------------------------------------------------------------------
__global__ __launch_bounds__(256) void k_kv_gemm(
    const __hip_bfloat16* __restrict__ Gb, const __hip_bfloat16* __restrict__ Wb,
    const float* __restrict__ in_b,
    __hip_bfloat16* __restrict__ Kp, __hip_bfloat16* __restrict__ Vp) {
  __shared__ unsigned short ldsD[64][72];
  const int t = threadIdx.x;
  const int w = t >> 6;
  const int lane = t & 63;
  const int col = lane & 15;
  const int quad = lane >> 4;
  const int bx = blockIdx.x;
  const int v0 = (bx >> 2) * 64;
  const int cg = bx & 3;

  const unsigned short* gRow =
      reinterpret_cast<const unsigned short*>(Gb) + (size_t)(v0 + w*16 + col)*CH + quad*8;
  short8 afrag[4];
  #pragma unroll
  for (int kq = 0; kq < 4; kq++)
    afrag[kq] = *reinterpret_cast<const short8*>(gRow + kq*32);

  float4v acc[4];
  #pragma unroll
  for (int j = 0; j < 4; j++) {
    const float bia = in_b[CH + cg*64 + j*16 + col];
    acc[j] = (float4v){bia, bia, bia, bia};
  }
  const unsigned short* wB = reinterpret_cast<const unsigned short*>(Wb);
  #pragma unroll
  for (int kq = 0; kq < 4; kq++) {
    #pragma unroll
    for (int j = 0; j < 4; j++) {
      const short8 bfrag = *reinterpret_cast<const short8*>(
          wB + (size_t)(cg*64 + j*16 + col)*CH + kq*32 + quad*8);
      acc[j] = __builtin_amdgcn_mfma_f32_16x16x32_bf16(afrag[kq], bfrag, acc[j], 0, 0, 0);
    }
  }
  #pragma unroll
  for (int j = 0; j < 4; j++)
    #pragma unroll
    for (int r = 0; r < 4; r++)
      ldsD[w*16 + quad*4 + r][j*16 + col] = f2bf(acc[j][r]);
  __syncthreads();
  const int row = t >> 2;
  const int cc  = (t & 3) * 16;
  const uint4 d0 = *reinterpret_cast<const uint4*>(&ldsD[row][cc]);
  const uint4 d1 = *reinterpret_cast<const uint4*>(&ldsD[row][cc+8]);
  __hip_bfloat16* dst = (cg < 2) ? Kp : Vp;
  uint4* out = reinterpret_cast<uint4*>(dst + (size_t)(v0 + row)*CH + (cg & 1)*64 + cc);
  out[0] = d0; out[1] = d1;
}

// ---------------------------------------------------------------------------
// Kernel 2: per-query — q = relu(qc@q_pos_w.T + b) @ wq.T + bq (fp32).
// ---------------------------------------------------------------------------
__global__ __launch_bounds__(256) void k_query(
    const float* __restrict__ qcoord,
    const float* __restrict__ qpw, const float* __restrict__ qpb,
    const float* __restrict__ in_w, const float* __restrict__ in_b,
    float* __restrict__ qout) {
  __shared__ float qf[16][CH];
  const int t = threadIdx.x;
  const int qbase = blockIdx.x * 16;
  #pragma unroll
  for (int i = 0; i < 8; i++) {
    const int e = t + 256*i;
    const int qv = e >> 7, c = e & 127;
    const int qq = qbase + qv;
    const float v = fmaf(qcoord[qq*3+0], qpw[c*3+0],
                    fmaf(qcoord[qq*3+1], qpw[c*3+1],
                    fmaf(qcoord[qq*3+2], qpw[c*3+2], qpb[c])));
    qf[qv][c] = fmaxf(v, 0.0f);
  }
  __syncthreads();
  const int oc = t & 127, half = t >> 7;
  const float* wrow = in_w + (size_t)oc * CH;
  const float bia = in_b[oc];
  float acc[8];
  #pragma unroll
  for (int v = 0; v < 8; v++) acc[v] = bia;
  for (int c = 0; c < CH; c += 4) {
    const float4 w4 = *reinterpret_cast<const float4*>(wrow + c);
    #pragma unroll
    for (int v = 0; v < 8; v++) {
      const float4 g4 = *reinterpret_cast<const float4*>(&qf[half*8+v][c]);
      acc[v] = fmaf(g4.x, w4.x, fmaf(g4.y, w4.y, fmaf(g4.z, w4.z, fmaf(g4.w, w4.w, acc[v]))));
    }
  }
  #pragma unroll
  for (int v = 0; v < 8; v++) qout[(size_t)(qbase + half*8 + v)*CH + oc] = acc[v];
}

// ---------------------------------------------------------------------------
// Kernel 3: attention — one block per query, bf16 K/V gathers (unchanged).
// ---------------------------------------------------------------------------
__global__ __launch_bounds__(256) void k_attn(
    const __hip_bfloat16* __restrict__ Kp, const __hip_bfloat16* __restrict__ Vp,
    const float* __restrict__ qg, const int* __restrict__ kidx,
    float* __restrict__ ctxg) {
  __shared__ float qs[CH];
  __shared__ int   js[KK];
  __shared__ float sc[8*100];
  __shared__ float red[4][CH];
  __shared__ float rden[8];
  const int n = blockIdx.x;
  const int t = threadIdx.x;
  if (t < CH) qs[t] = qg[(size_t)n*CH + t];
  if (t < KK) js[t] = kidx[(size_t)n*KK + t];
  __syncthreads();
  #pragma unroll
  for (int i = 0; i < 3; i++) {
    const int e = t + 256*i;
    const int k = e >> 3, h = e & 7;
    const int j = js[k];
    float s;
    if (j < 0) {
      s = -1e9f;
    } else {
      const uint4* kr = reinterpret_cast<const uint4*>(Kp + (size_t)j*CH + h*16);
      const uint4 ka = kr[0], kb = kr[1];
      const float* qh = qs + h*16;
      s = 0.0f;
      s = fmaf(qh[0],  bflo(ka.x), s); s = fmaf(qh[1],  bfhi(ka.x), s);
      s = fmaf(qh[2],  bflo(ka.y), s); s = fmaf(qh[3],  bfhi(ka.y), s);
      s = fmaf(qh[4],  bflo(ka.z), s); s = fmaf(qh[5],  bfhi(ka.z), s);
      s = fmaf(qh[6],  bflo(ka.w), s); s = fmaf(qh[7],  bfhi(ka.w), s);
      s = fmaf(qh[8],  bflo(kb.x), s); s = fmaf(qh[9],  bfhi(kb.x), s);
      s = fmaf(qh[10], bflo(kb.y), s); s = fmaf(qh[11], bfhi(kb.y), s);
      s = fmaf(qh[12], bflo(kb.z), s); s = fmaf(qh[13], bfhi(kb.z), s);
      s = fmaf(qh[14], bflo(kb.w), s); s = fmaf(qh[15], bfhi(kb.w), s);
      s *= 0.25f;
    }
    sc[h*100 + k] = s;
  }
  __syncthreads();
  if (t < 128) {
    const int h = t >> 4, l = t & 15;
    float mx = -3e38f;
    for (int k = l; k < KK; k += 16) mx = fmaxf(mx, sc[h*100+k]);
    #pragma unroll
    for (int m = 8; m >= 1; m >>= 1) mx = fmaxf(mx, __shfl_xor(mx, m));
    float sum = 0.0f;
    for (int k = l; k < KK; k += 16) {
      const float p = __expf(sc[h*100+k] - mx);
      sc[h*100+k] = p;
      sum += p;
    }
    #pragma unroll
    for (int m = 8; m >= 1; m >>= 1) sum += __shfl_xor(sum, m);
    if (l == 0) rden[h] = 1.0f / sum;
  }
  __syncthreads();
  {
    const int p = t & 63, grp = t >> 6;
    const int h = p >> 3;
    float a0 = 0.0f, a1 = 0.0f;
    const int k0 = grp * 24;
    for (int k = k0; k < k0 + 24; k++) {
      const int j = js[k];
      if (j >= 0) {
        const unsigned vv = reinterpret_cast<const unsigned*>(Vp + (size_t)j*CH)[p];
        const float w = sc[h*100+k];
        a0 = fmaf(w, bflo(vv), a0);
        a1 = fmaf(w, bfhi(vv), a1);
      }
    }
    *reinterpret_cast<float2*>(&red[grp][2*p]) = make_float2(a0, a1);
  }
  __syncthreads();
  if (t < CH) {
    ctxg[(size_t)n*CH + t] =
        (red[0][t] + red[1][t] + red[2][t] + red[3][t]) * rden[t>>4];
  }
}

// ---------------------------------------------------------------------------
// Kernel 4: epilogue via MFMA bf16. 16 queries/block, 4 waves.
// attend = ctx@ow.T+ob (fp32 in LDS); LN2 -> hb bf16; a1=relu(hb@l1w.T+l1b);
// x = attend + a1@l2w.T+l2b; out = relu(x@fw.T+fb).
// A-frag LDS rows padded +8 bf16 (stride 272B -> bank stride 4, 2-way=free).
// ---------------------------------------------------------------------------
__global__ __launch_bounds__(256) void k_epi(
    const float* __restrict__ ctxg, const __hip_bfloat16* __restrict__ Eb,
    const float* __restrict__ ob,
    const float* __restrict__ n2g, const float* __restrict__ n2b,
    const float* __restrict__ l1b, const float* __restrict__ l2b,
    const float* __restrict__ fb,
    float* __restrict__ outp) {
  __shared__ unsigned short csb[16][136];   // ctx bf16
  __shared__ float attnS[16][132];          // attend fp32 (residual)
  __shared__ unsigned short hb[16][136];    // LN2 out bf16
  __shared__ unsigned short a1b[16][264];   // relu(lin1) bf16
  __shared__ unsigned short xb[16][136];    // attend+act bf16
  const unsigned short* owb  = reinterpret_cast<const unsigned short*>(Eb);
  const unsigned short* l1wb = owb + 16384;
  const unsigned short* l2wb = owb + 49152;
  const unsigned short* fwb  = owb + 81920;

  const int t = threadIdx.x;
  const int w = t >> 6;
  const int lane = t & 63;
  const int col = lane & 15;
  const int quad = lane >> 4;
  const int qbase = blockIdx.x * 16;

  { // Phase A: stage ctx -> csb bf16
    const int e = t * 8;
    const int row = e >> 7, cc = e & 127;
    const float4* src = reinterpret_cast<const float4*>(ctxg + (size_t)(qbase+row)*CH + cc);
    const float4 x0 = src[0], x1 = src[1];
    *reinterpret_cast<uint4*>(&csb[row][cc]) =
        make_uint4(pack2(x0.x,x0.y), pack2(x0.z,x0.w), pack2(x1.x,x1.y), pack2(x1.z,x1.w));
  }
  __syncthreads();
  { // Phase B: attend = ctx @ ow.T + ob -> attnS fp32
    short8 af[4];
    #pragma unroll
    for (int kq = 0; kq < 4; kq++)
      af[kq] = *reinterpret_cast<const short8*>(&csb[col][quad*8 + kq*32]);
    #pragma unroll
    for (int j = 0; j < 2; j++) {
      const int n0 = w*32 + j*16;
      const float bia = ob[n0 + col];
      float4v acc = (float4v){bia, bia, bia, bia};
      #pragma unroll
      for (int kq = 0; kq < 4; kq++) {
        const short8 bf = *reinterpret_cast<const short8*>(
            owb + (size_t)(n0 + col)*CH + kq*32 + quad*8);
        acc = __builtin_amdgcn_mfma_f32_16x16x32_bf16(af[kq], bf, acc, 0, 0, 0);
      }
      #pragma unroll
      for (int r = 0; r < 4; r++) attnS[quad*4 + r][n0 + col] = acc[r];
    }
  }
  __syncthreads();
  { // Phase C: LayerNorm2 on attnS -> hb bf16
    const int row = t >> 4, l = t & 15;
    float s = 0.0f, ss = 0.0f;
    #pragma unroll
    for (int c = l; c < CH; c += 16) { const float x = attnS[row][c]; s += x; ss += x*x; }
    #pragma unroll
    for (int m = 8; m >= 1; m >>= 1) { s += __shfl_xor(s, m); ss += __shfl_xor(ss, m); }
    const float mean = s * (1.0f/CH);
    const float var  = ss * (1.0f/CH) - mean*mean;
    const float rstd = 1.0f / sqrtf(var + 1e-5f);
    #pragma unroll
    for (int c = l; c < CH; c += 16)
      hb[row][c] = f2bf((attnS[row][c] - mean) * rstd * n2g[c] + n2b[c]);
  }
  __syncthreads();
  { // Phase D: a1 = relu(h @ l1w.T + l1b) -> a1b bf16  (N=256)
    short8 af[4];
    #pragma unroll
    for (int kq = 0; kq < 4; kq++)
      af[kq] = *reinterpret_cast<const short8*>(&hb[col][quad*8 + kq*32]);
    #pragma unroll
    for (int j = 0; j < 4; j++) {
      const int n0 = w*64 + j*16;
      const float bia = l1b[n0 + col];
      float4v acc = (float4v){bia, bia, bia, bia};
      #pragma unroll
      for (int kq = 0; kq < 4; kq++) {
        const short8 bf = *reinterpret_cast<const short8*>(
            l1wb + (size_t)(n0 + col)*CH + kq*32 + quad*8);
        acc = __builtin_amdgcn_mfma_f32_16x16x32_bf16(af[kq], bf, acc, 0, 0, 0);
      }
      #pragma unroll
      for (int r = 0; r < 4; r++)
        a1b[quad*4 + r][n0 + col] = f2bf(fmaxf(acc[r], 0.0f));
    }
  }
  __syncthreads();
  { // Phase E: x = attend + a1 @ l2w.T + l2b -> xb bf16  (K=256)
    short8 af[8];
    #pragma unroll
    for (int kq = 0; kq < 8; kq++)
      af[kq] = *reinterpret_cast<const short8*>(&a1b[col][quad*8 + kq*32]);
    #pragma unroll
    for (int j = 0; j < 2; j++) {
      const int n0 = w*32 + j*16;
      const float bia = l2b[n0 + col];
      float4v acc = (float4v){bia, bia, bia, bia};
      #pragma unroll
      for (int kq = 0; kq < 8; kq++) {
        const short8 bf = *reinterpret_cast<const short8*>(
            l2wb + (size_t)(n0 + col)*FFD + kq*32 + quad*8);
        acc = __builtin_amdgcn_mfma_f32_16x16x32_bf16(af[kq], bf, acc, 0, 0, 0);
      }
      #pragma unroll
      for (int r = 0; r < 4; r++)
        xb[quad*4 + r][n0 + col] = f2bf(acc[r] + attnS[quad*4 + r][n0 + col]);
    }
  }
  __syncthreads();
  { // Phase F: out = relu(x @ fw.T + fb) -> global
    short8 af[4];
    #pragma unroll
    for (int kq = 0; kq < 4; kq++)
      af[kq] = *reinterpret_cast<const short8*>(&xb[col][quad*8 + kq*32]);
    #pragma unroll
    for (int j = 0; j < 2; j++) {
      const int n0 = w*32 + j*16;
      const float bia = fb[n0 + col];
      float4v acc = (float4v){bia, bia, bia, bia};
      #pragma unroll
      for (int kq = 0; kq < 4; kq++) {
        const short8 bf = *reinterpret_cast<const short8*>(
            fwb + (size_t)(n0 + col)*CH + kq*32 + quad*8);
        acc = __builtin_amdgcn_mfma_f32_16x16x32_bf16(af[kq], bf, acc, 0, 0, 0);
      }
      #pragma unroll
      for (int r = 0; r < 4; r++)
        outp[(size_t)(qbase + quad*4 + r)*CH + n0 + col] = fmaxf(acc[r], 0.0f);
    }
  }
}

// ---------------------------------------------------------------------------
extern "C" void kernel_launch(void* const* d_in, const int* in_sizes, int n_in,
                              void* d_out, int out_size, void* d_ws, size_t ws_size,
                              hipStream_t stream) {
  const float* vfeat  = (const float*)d_in[0];
  const float* vcoord = (const float*)d_in[1];
  const float* qcoord = (const float*)d_in[2];
  const int*   kidx   = (const int*)  d_in[3];
  const float* n1g    = (const float*)d_in[4];
  const float* n1b    = (const float*)d_in[5];
  const float* qpw    = (const float*)d_in[6];
  const float* qpb    = (const float*)d_in[7];
  const float* kpw    = (const float*)d_in[8];
  const float* kpb    = (const float*)d_in[9];
  const float* in_w   = (const float*)d_in[10];
  const float* in_b   = (const float*)d_in[11];
  const float* out_w  = (const float*)d_in[12];
  const float* out_b  = (const float*)d_in[13];
  const float* n2g    = (const float*)d_in[14];
  const float* n2b    = (const float*)d_in[15];
  const float* l1w    = (const float*)d_in[16];
  const float* l1b    = (const float*)d_in[17];
  const float* l2w    = (const float*)d_in[18];
  const float* l2b    = (const float*)d_in[19];
  const float* fw     = (const float*)d_in[20];
  const float* fb     = (const float*)d_in[21];
  float* out = (float*)d_out;

  __hip_bfloat16* Kp = (__hip_bfloat16*)d_ws;          // NVOX*CH bf16
  __hip_bfloat16* Vp = Kp + (size_t)NVOX*CH;           // NVOX*CH bf16
  __hip_bfloat16* Gb = Vp + (size_t)NVOX*CH;           // NVOX*CH bf16
  __hip_bfloat16* Wb = Gb + (size_t)NVOX*CH;           // 256*CH bf16
  __hip_bfloat16* Eb = Wb + (size_t)2*CH*CH;           // 98304 bf16 epi weights
  float* qb = (float*)(Eb + 98304);                    // NQRY*CH f32
  float* cx = qb + (size_t)NQRY*CH;                    // NQRY*CH f32

  k_prep   <<<NVOX/16 + 32, 256, 0, stream>>>(vfeat, vcoord, n1g, n1b, kpw, kpb,
                                              in_w, out_w, l1w, l2w, fw, Gb, Wb, Eb);
  k_query  <<<NQRY/16, 256, 0, stream>>>(qcoord, qpw, qpb, in_w, in_b, qb);
  k_kv_gemm<<<(NVOX/64)*4, 256, 0, stream>>>(Gb, Wb, in_b, Kp, Vp);
  k_attn   <<<NQRY,    256, 0, stream>>>(Kp, Vp, qb, kidx, cx);
  k_epi    <<<NQRY/16, 256, 0, stream>>>(cx, Eb, out_b, n2g, n2b, l1b, l2b, fb, out);
}